// Round 1
// baseline (96.865 us; speedup 1.0000x reference)
//
#include <hip/hip_runtime.h>
#include <math.h>

#define HDIM 1024
#define BDIM 64
#define NDIM 512
#define NEGC 1e30f

// ---------------- K1: k_score[b][n] = dot(K[b][n][:], Wk) -------------------
// grid 4096 blocks x 256 threads; each wave computes 2 dot products.
__global__ __launch_bounds__(256) void k_scores(const float* __restrict__ Kmat,
                                                const float* __restrict__ Wk,
                                                float* __restrict__ scores) {
    int wave = threadIdx.x >> 6;
    int lane = threadIdx.x & 63;
    int base = blockIdx.x * 8 + wave * 2;   // global n-pair start (b*512+n)
    int b = base >> 9;
    int n0 = base & 511;

    const float4* wk4 = (const float4*)Wk;
    const float4* kp0 = (const float4*)(Kmat + (size_t)(b * 512 + n0) * HDIM);
    const float4* kp1 = (const float4*)(Kmat + (size_t)(b * 512 + n0 + 1) * HDIM);

    float s0 = 0.f, s1 = 0.f;
#pragma unroll
    for (int i = 0; i < 4; ++i) {
        float4 wv = wk4[i * 64 + lane];
        float4 k0 = kp0[i * 64 + lane];
        float4 k1 = kp1[i * 64 + lane];
        s0 = fmaf(k0.x, wv.x, s0); s0 = fmaf(k0.y, wv.y, s0);
        s0 = fmaf(k0.z, wv.z, s0); s0 = fmaf(k0.w, wv.w, s0);
        s1 = fmaf(k1.x, wv.x, s1); s1 = fmaf(k1.y, wv.y, s1);
        s1 = fmaf(k1.z, wv.z, s1); s1 = fmaf(k1.w, wv.w, s1);
    }
#pragma unroll
    for (int off = 32; off; off >>= 1) {
        s0 += __shfl_xor(s0, off);
        s1 += __shfl_xor(s1, off);
    }
    if (lane == 0) {
        scores[b * 512 + n0]     = s0;
        scores[b * 512 + n0 + 1] = s1;
    }
}

// ---------------- K2: masked softmax per b ----------------------------------
// grid 64 blocks x 512 threads. Writes w to d_out[0:B*N), and w*s, w*o to ws.
__global__ __launch_bounds__(512) void k_softmax(const float* __restrict__ scores,
                                                 const int* __restrict__ adj,
                                                 const int* __restrict__ smask,
                                                 const int* __restrict__ omask,
                                                 float* __restrict__ w_out,
                                                 float* __restrict__ wS,
                                                 float* __restrict__ wO) {
    __shared__ float red_m[8];
    __shared__ float red_s[8];
    int b = blockIdx.x;
    int n = threadIdx.x;
    int idx = b * 512 + n;
    int wave = threadIdx.x >> 6;
    int lane = threadIdx.x & 63;

    float sc = scores[idx];
    float alpha = adj[idx] ? sc : (sc - NEGC);

    float m = alpha;
#pragma unroll
    for (int off = 32; off; off >>= 1) m = fmaxf(m, __shfl_xor(m, off));
    if (lane == 0) red_m[wave] = m;
    __syncthreads();
    float mm = red_m[0];
#pragma unroll
    for (int i = 1; i < 8; ++i) mm = fmaxf(mm, red_m[i]);

    float e = expf(alpha - mm);
    float t = e;
#pragma unroll
    for (int off = 32; off; off >>= 1) t += __shfl_xor(t, off);
    if (lane == 0) red_s[wave] = t;
    __syncthreads();
    float tot = red_s[0];
#pragma unroll
    for (int i = 1; i < 8; ++i) tot += red_s[i];

    float w = e / tot;
    w_out[idx] = w;
    wS[idx] = smask[idx] ? w : 0.f;
    wO[idx] = omask[idx] ? w : 0.f;
}

// ---------------- K3: u-partials: p[nc][b][h] = sum_{n in chunk} w*V --------
// grid 512 (b*8+nc) x 256 threads; thread owns float4 at h=4*tid.
__global__ __launch_bounds__(256) void k_weightv(const float* __restrict__ V,
                                                 const float* __restrict__ wS,
                                                 const float* __restrict__ wO,
                                                 float* __restrict__ p0,
                                                 float* __restrict__ p1) {
    int b = blockIdx.x >> 3;
    int nc = blockIdx.x & 7;
    int h4 = threadIdx.x;

    const float4* vp = (const float4*)(V + ((size_t)(b * 512 + nc * 64)) * HDIM);
    float4 a0 = {0.f, 0.f, 0.f, 0.f};
    float4 a1 = {0.f, 0.f, 0.f, 0.f};
#pragma unroll 4
    for (int nn = 0; nn < 64; ++nn) {
        float ws = wS[b * 512 + nc * 64 + nn];
        float wo = wO[b * 512 + nc * 64 + nn];
        float4 v = vp[nn * 256 + h4];
        a0.x = fmaf(ws, v.x, a0.x); a0.y = fmaf(ws, v.y, a0.y);
        a0.z = fmaf(ws, v.z, a0.z); a0.w = fmaf(ws, v.w, a0.w);
        a1.x = fmaf(wo, v.x, a1.x); a1.y = fmaf(wo, v.y, a1.y);
        a1.z = fmaf(wo, v.z, a1.z); a1.w = fmaf(wo, v.w, a1.w);
    }
    size_t o = ((size_t)(nc * 64 + b)) * HDIM + h4 * 4;
    *(float4*)(p0 + o) = a0;
    *(float4*)(p1 + o) = a1;
}

// ---------------- K4: reduce 8 n-chunk partials -> u0,u1 [b][h] -------------
// grid 64 blocks x 256 threads (thread = float4 slot).
__global__ __launch_bounds__(256) void k_redu(const float* __restrict__ p0,
                                              const float* __restrict__ p1,
                                              float* __restrict__ u0,
                                              float* __restrict__ u1) {
    int b = blockIdx.x;
    int h4 = threadIdx.x;
    float4 a0 = {0.f, 0.f, 0.f, 0.f};
    float4 a1 = {0.f, 0.f, 0.f, 0.f};
#pragma unroll
    for (int nc = 0; nc < 8; ++nc) {
        size_t o = ((size_t)(nc * 64 + b)) * HDIM + h4 * 4;
        float4 v0 = *(const float4*)(p0 + o);
        float4 v1 = *(const float4*)(p1 + o);
        a0.x += v0.x; a0.y += v0.y; a0.z += v0.z; a0.w += v0.w;
        a1.x += v1.x; a1.y += v1.y; a1.z += v1.z; a1.w += v1.w;
    }
    *(float4*)(u0 + (size_t)b * HDIM + h4 * 4) = a0;
    *(float4*)(u1 + (size_t)b * HDIM + h4 * 4) = a1;
}

// ---------------- K5: split-k GEMM partials: pOut[kc][h][b] -----------------
// out[b][h] = sum_k u0[b][k]*Wr0[h][k] + u1[b][k]*Wr1[h][k]
// grid 256 blocks (ht*16+kc) x 256 threads. lane=b, wave owns 16 h rows.
// Wr rows are wave-uniform -> scalar (s_load) reads; u chunk staged in LDS
// with f4-granular XOR swizzle for conflict-free ds_read_b128.
__global__ __launch_bounds__(256) void k_out(const float* __restrict__ u0,
                                             const float* __restrict__ u1,
                                             const float* __restrict__ Wr0,
                                             const float* __restrict__ Wr1,
                                             float* __restrict__ pOut) {
    __shared__ float lds[64 * 128];
    int tid = threadIdx.x;
    int ht = blockIdx.x >> 4;   // 0..15  (h tile of 64)
    int kc = blockIdx.x & 15;   // 0..15  (k chunk of 128, over [u0|u1])
    const float* usrc = (kc < 8) ? u0 : u1;
    const float* wsrc = (kc < 8) ? Wr0 : Wr1;
    int koff = (kc & 7) * 128;
    int h0 = ht * 64;

    // stage U[0:64][koff:koff+128] into LDS, swizzled: f4 col' = col ^ (row&7)
    {
        int c4 = tid & 31;
        int r2 = tid >> 5;
#pragma unroll
        for (int i = 0; i < 8; ++i) {
            int row = i * 8 + r2;
            float4 v = *(const float4*)(usrc + (size_t)row * HDIM + koff + c4 * 4);
            *(float4*)&lds[row * 128 + ((c4 ^ (row & 7)) << 2)] = v;
        }
    }
    __syncthreads();

    int b = tid & 63;
    int wu = __builtin_amdgcn_readfirstlane(tid >> 6);
    int hbase = h0 + wu * 16;
    const float* wrow = wsrc + (size_t)hbase * HDIM + koff;

    float acc[16];
#pragma unroll
    for (int j = 0; j < 16; ++j) acc[j] = 0.f;

#pragma unroll 4
    for (int k4 = 0; k4 < 32; ++k4) {
        float4 uv = *(float4*)&lds[b * 128 + ((k4 ^ (b & 7)) << 2)];
#pragma unroll
        for (int j = 0; j < 16; ++j) {
            float4 wv = *(const float4*)(wrow + (size_t)j * HDIM + k4 * 4);
            acc[j] = fmaf(uv.x, wv.x, acc[j]);
            acc[j] = fmaf(uv.y, wv.y, acc[j]);
            acc[j] = fmaf(uv.z, wv.z, acc[j]);
            acc[j] = fmaf(uv.w, wv.w, acc[j]);
        }
    }
#pragma unroll
    for (int j = 0; j < 16; ++j)
        pOut[((size_t)kc * HDIM + hbase + j) * 64 + b] = acc[j];
}

// ---------------- K6: reduce 16 k-chunks -> attn_sum[b][h] ------------------
// grid 256 blocks x 256 threads (4 h x 64 b per block).
__global__ __launch_bounds__(256) void k_redout(const float* __restrict__ pOut,
                                                float* __restrict__ out1) {
    int tid = threadIdx.x;
    int b = tid & 63;
    int h = blockIdx.x * 4 + (tid >> 6);
    float acc = 0.f;
#pragma unroll
    for (int kc = 0; kc < 16; ++kc)
        acc += pOut[((size_t)kc * HDIM + h) * 64 + b];
    out1[(size_t)b * HDIM + h] = acc;
}

extern "C" void kernel_launch(void* const* d_in, const int* in_sizes, int n_in,
                              void* d_out, int out_size, void* d_ws, size_t ws_size,
                              hipStream_t stream) {
    const float* Kmat  = (const float*)d_in[1];
    const float* V     = (const float*)d_in[2];
    const int*   adj   = (const int*)d_in[3];
    const int*   smask = (const int*)d_in[4];
    const int*   omask = (const int*)d_in[5];
    const float* Watt  = (const float*)d_in[6];
    const float* Wr0   = (const float*)d_in[8];
    const float* Wr1   = (const float*)d_in[9];
    float* out = (float*)d_out;
    float* ws  = (float*)d_ws;

    // ws layout (float offsets)
    float* scores = ws;                 //  64*512
    float* wS     = ws + 32768;         //  64*512
    float* wO     = ws + 65536;         //  64*512
    float* p0     = ws + 98304;         //  8*64*1024
    float* p1     = ws + 622592;        //  8*64*1024
    float* u0     = ws + 1146880;       //  64*1024
    float* u1     = ws + 1212416;       //  64*1024
    float* pOut   = ws + 1277952;       //  16*1024*64
    const float* Wk = Watt + HDIM;      // second half of W_att

    k_scores <<<4096, 256, 0, stream>>>(Kmat, Wk, scores);
    k_softmax<<<  64, 512, 0, stream>>>(scores, adj, smask, omask, out, wS, wO);
    k_weightv<<< 512, 256, 0, stream>>>(V, wS, wO, p0, p1);
    k_redu   <<<  64, 256, 0, stream>>>(p0, p1, u0, u1);
    k_out    <<< 256, 256, 0, stream>>>(u0, u1, Wr0, Wr1, pOut);
    k_redout <<< 256, 256, 0, stream>>>(pOut, out + 32768);
}

// Round 2
// 94.313 us; speedup vs baseline: 1.0271x; 1.0271x over previous
//
#include <hip/hip_runtime.h>
#include <math.h>

#define HDIM 1024
#define BDIM 64
#define NDIM 512

// ---------------- K1: fused score+exp+mask+V-weighting ----------------------
// grid 1024 blocks (b*16 + nc), 256 threads. Chunk = 32 n-rows.
// Phase 1: per-wave dot(K[row], Wk) for 8 rows -> e = adj ? exp(s) : 0.
// Phase 2: stream V chunk, accumulate p0 += e*s_mask*V, p1 += e*o_mask*V.
// Normalization 1/sum(e) is deferred (softmax factorization).
__global__ __launch_bounds__(256) void k_fused(const float* __restrict__ Kmat,
                                               const float* __restrict__ V,
                                               const int* __restrict__ adj,
                                               const int* __restrict__ smask,
                                               const int* __restrict__ omask,
                                               const float* __restrict__ Wk,
                                               float* __restrict__ e_out,
                                               float* __restrict__ p0,
                                               float* __restrict__ p1) {
    __shared__ float2 eso[32];
    __shared__ float eLDS[32];
    __shared__ int mAdj[32], mS[32], mO[32];
    int b = blockIdx.x >> 4;
    int nc = blockIdx.x & 15;
    int tid = threadIdx.x;
    int wave = tid >> 6, lane = tid & 63;
    int gbase = b * 512 + nc * 32;

    if (tid < 32) {
        mAdj[tid] = adj[gbase + tid];
        mS[tid]   = smask[gbase + tid];
        mO[tid]   = omask[gbase + tid];
    }

    const float4* wk4 = (const float4*)Wk;
    float4 wk[4];
#pragma unroll
    for (int i = 0; i < 4; ++i) wk[i] = wk4[i * 64 + lane];

    __syncthreads();

    // phase 1: 8 rows per wave
    const float* Kbase = Kmat + ((size_t)(gbase + wave * 8)) * HDIM;
#pragma unroll
    for (int r = 0; r < 8; ++r) {
        const float4* kp = (const float4*)(Kbase + (size_t)r * HDIM);
        float s = 0.f;
#pragma unroll
        for (int i = 0; i < 4; ++i) {
            float4 kv = kp[i * 64 + lane];
            s = fmaf(kv.x, wk[i].x, s); s = fmaf(kv.y, wk[i].y, s);
            s = fmaf(kv.z, wk[i].z, s); s = fmaf(kv.w, wk[i].w, s);
        }
#pragma unroll
        for (int off = 32; off; off >>= 1) s += __shfl_xor(s, off);
        int row = wave * 8 + r;
        if (lane == 0) {
            float e = mAdj[row] ? expf(s) : 0.f;
            eLDS[row] = e;
            eso[row] = make_float2(mS[row] ? e : 0.f, mO[row] ? e : 0.f);
        }
    }
    __syncthreads();
    if (tid < 32) e_out[gbase + tid] = eLDS[tid];

    // phase 2: stream V chunk
    const float4* vp = (const float4*)(V + (size_t)gbase * HDIM);
    float4 a0 = {0.f, 0.f, 0.f, 0.f};
    float4 a1 = {0.f, 0.f, 0.f, 0.f};
#pragma unroll 8
    for (int nn = 0; nn < 32; ++nn) {
        float2 w2 = eso[nn];
        float4 v = vp[nn * 256 + tid];
        a0.x = fmaf(w2.x, v.x, a0.x); a0.y = fmaf(w2.x, v.y, a0.y);
        a0.z = fmaf(w2.x, v.z, a0.z); a0.w = fmaf(w2.x, v.w, a0.w);
        a1.x = fmaf(w2.y, v.x, a1.x); a1.y = fmaf(w2.y, v.y, a1.y);
        a1.z = fmaf(w2.y, v.z, a1.z); a1.w = fmaf(w2.y, v.w, a1.w);
    }
    size_t o = ((size_t)(nc * 64 + b)) * HDIM + tid * 4;
    *(float4*)(p0 + o) = a0;
    *(float4*)(p1 + o) = a1;
}

// ---------------- K2: softmax denom + attn_weight + u reduce+normalize ------
// grid 64 blocks (per b) x 512 threads.
__global__ __launch_bounds__(512) void k_norm_redu(const float* __restrict__ e,
                                                   const float* __restrict__ p0,
                                                   const float* __restrict__ p1,
                                                   float* __restrict__ w_out,
                                                   float* __restrict__ u0,
                                                   float* __restrict__ u1) {
    __shared__ float red[8];
    int b = blockIdx.x;
    int tid = threadIdx.x;
    int wave = tid >> 6, lane = tid & 63;

    float ev = e[b * 512 + tid];
    float t = ev;
#pragma unroll
    for (int off = 32; off; off >>= 1) t += __shfl_xor(t, off);
    if (lane == 0) red[wave] = t;
    __syncthreads();
    float tot = red[0];
#pragma unroll
    for (int i = 1; i < 8; ++i) tot += red[i];
    float inv = 1.f / tot;
    w_out[b * 512 + tid] = ev * inv;

    // reduce 16 n-chunk partials, scale by inv
    const float* psrc = (tid < 256) ? p0 : p1;
    float* udst = (tid < 256) ? u0 : u1;
    int h4 = tid & 255;
    float4 a = {0.f, 0.f, 0.f, 0.f};
#pragma unroll
    for (int nc = 0; nc < 16; ++nc) {
        size_t o = ((size_t)(nc * 64 + b)) * HDIM + h4 * 4;
        float4 v = *(const float4*)(psrc + o);
        a.x += v.x; a.y += v.y; a.z += v.z; a.w += v.w;
    }
    a.x *= inv; a.y *= inv; a.z *= inv; a.w *= inv;
    *(float4*)(udst + (size_t)b * HDIM + h4 * 4) = a;
}

// ---------------- K3: split-k GEMM partials: pOut[kc][h][b] -----------------
// out[b][h] = sum_k u0[b][k]*Wr0[h][k] + u1[b][k]*Wr1[h][k]
// grid 256 blocks (ht*16+kc) x 256 threads. lane=b, wave owns 16 h rows.
__global__ __launch_bounds__(256) void k_out(const float* __restrict__ u0,
                                             const float* __restrict__ u1,
                                             const float* __restrict__ Wr0,
                                             const float* __restrict__ Wr1,
                                             float* __restrict__ pOut) {
    __shared__ float lds[64 * 128];
    int tid = threadIdx.x;
    int ht = blockIdx.x >> 4;   // 0..15  (h tile of 64)
    int kc = blockIdx.x & 15;   // 0..15  (k chunk of 128, over [u0|u1])
    const float* usrc = (kc < 8) ? u0 : u1;
    const float* wsrc = (kc < 8) ? Wr0 : Wr1;
    int koff = (kc & 7) * 128;
    int h0 = ht * 64;

    // stage U[0:64][koff:koff+128] into LDS, swizzled: f4 col' = col ^ (row&7)
    {
        int c4 = tid & 31;
        int r2 = tid >> 5;
#pragma unroll
        for (int i = 0; i < 8; ++i) {
            int row = i * 8 + r2;
            float4 v = *(const float4*)(usrc + (size_t)row * HDIM + koff + c4 * 4);
            *(float4*)&lds[row * 128 + ((c4 ^ (row & 7)) << 2)] = v;
        }
    }
    __syncthreads();

    int b = tid & 63;
    int wu = __builtin_amdgcn_readfirstlane(tid >> 6);
    int hbase = h0 + wu * 16;
    const float* wrow = wsrc + (size_t)hbase * HDIM + koff;

    float acc[16];
#pragma unroll
    for (int j = 0; j < 16; ++j) acc[j] = 0.f;

#pragma unroll 4
    for (int k4 = 0; k4 < 32; ++k4) {
        float4 uv = *(float4*)&lds[b * 128 + ((k4 ^ (b & 7)) << 2)];
#pragma unroll
        for (int j = 0; j < 16; ++j) {
            float4 wv = *(const float4*)(wrow + (size_t)j * HDIM + k4 * 4);
            acc[j] = fmaf(uv.x, wv.x, acc[j]);
            acc[j] = fmaf(uv.y, wv.y, acc[j]);
            acc[j] = fmaf(uv.z, wv.z, acc[j]);
            acc[j] = fmaf(uv.w, wv.w, acc[j]);
        }
    }
#pragma unroll
    for (int j = 0; j < 16; ++j)
        pOut[((size_t)kc * HDIM + hbase + j) * 64 + b] = acc[j];
}

// ---------------- K4: reduce 16 k-chunks -> attn_sum[b][h] ------------------
// grid 256 blocks x 256 threads (4 h x 64 b per block).
__global__ __launch_bounds__(256) void k_redout(const float* __restrict__ pOut,
                                                float* __restrict__ out1) {
    int tid = threadIdx.x;
    int b = tid & 63;
    int h = blockIdx.x * 4 + (tid >> 6);
    float acc = 0.f;
#pragma unroll
    for (int kc = 0; kc < 16; ++kc)
        acc += pOut[((size_t)kc * HDIM + h) * 64 + b];
    out1[(size_t)b * HDIM + h] = acc;
}

extern "C" void kernel_launch(void* const* d_in, const int* in_sizes, int n_in,
                              void* d_out, int out_size, void* d_ws, size_t ws_size,
                              hipStream_t stream) {
    const float* Kmat  = (const float*)d_in[1];
    const float* V     = (const float*)d_in[2];
    const int*   adj   = (const int*)d_in[3];
    const int*   smask = (const int*)d_in[4];
    const int*   omask = (const int*)d_in[5];
    const float* Watt  = (const float*)d_in[6];
    const float* Wr0   = (const float*)d_in[8];
    const float* Wr1   = (const float*)d_in[9];
    float* out = (float*)d_out;
    float* ws  = (float*)d_ws;

    // ws layout (float offsets)
    float* e    = ws;                 //  64*512             = 32768
    float* p0   = ws + 32768;         //  16*64*1024         = 1048576
    float* p1   = ws + 1081344;       //  16*64*1024         = 1048576
    float* u0   = ws + 2129920;       //  64*1024            = 65536
    float* u1   = ws + 2195456;       //  64*1024            = 65536
    float* pOut = ws + 2260992;       //  16*1024*64         = 1048576
    const float* Wk = Watt + HDIM;    // second half of W_att

    k_fused    <<<1024, 256, 0, stream>>>(Kmat, V, adj, smask, omask, Wk, e, p0, p1);
    k_norm_redu<<<  64, 512, 0, stream>>>(e, p0, p1, out, u0, u1);
    k_out      <<< 256, 256, 0, stream>>>(u0, u1, Wr0, Wr1, pOut);
    k_redout   <<< 256, 256, 0, stream>>>(pOut, out + 32768);
}